// Round 1
// baseline (334.038 us; speedup 1.0000x reference)
//
#include <hip/hip_runtime.h>
#include <hip/hip_bf16.h>
#include <math.h>

typedef __attribute__((ext_vector_type(8))) short short8;
typedef __attribute__((ext_vector_type(8))) unsigned short ushort8;
typedef __attribute__((ext_vector_type(4))) float f32x4;

#define T_SEQ 4096
#define D_MODEL 2048
#define N_HEADS 16
#define N_KV 8
#define HEAD_DIM 128
#define QSCALE 0.08838834764831845f

__device__ __forceinline__ float bf2f(unsigned short u) {
  union { unsigned int i; float f; } x; x.i = ((unsigned int)u) << 16; return x.f;
}
__device__ __forceinline__ unsigned short f2bf(float f) {
  union { float f; unsigned int i; } x; x.f = f;
  unsigned int i = x.i;
  unsigned int r = i + 0x7fffu + ((i >> 16) & 1u);
  return (unsigned short)(r >> 16);
}

// ---------------- x (f32) -> bf16 ----------------
__global__ __launch_bounds__(256) void cvt_x_kernel(const float* __restrict__ x,
                                                    unsigned short* __restrict__ xb) {
  int idx = blockIdx.x * 256 + threadIdx.x;   // one thread = 8 elements
  const float4* p = reinterpret_cast<const float4*>(x) + (size_t)idx * 2;
  float4 a = p[0], b = p[1];
  ushort8 o;
  o[0] = f2bf(a.x); o[1] = f2bf(a.y); o[2] = f2bf(a.z); o[3] = f2bf(a.w);
  o[4] = f2bf(b.x); o[5] = f2bf(b.y); o[6] = f2bf(b.z); o[7] = f2bf(b.w);
  reinterpret_cast<ushort8*>(xb)[idx] = o;
}

// ---------------- RoPE sin/cos table ----------------
__global__ __launch_bounds__(256) void rope_table_kernel(const int* __restrict__ segpos,
                                                         float2* __restrict__ tab) {
  int idx = blockIdx.x * 256 + threadIdx.x;   // t*64 + i
  int t = idx >> 6, i = idx & 63;
  float pos = (float)segpos[t];
  float ts = powf(10000.f, (float)(2 * i) / 128.f);
  float ang = pos / ts;
  tab[idx] = make_float2(sinf(ang), cosf(ang));
}

// ---------------- f32 [R][C] -> bf16 [C][R] transpose (batched) ----------------
__global__ __launch_bounds__(256) void transpose_f32_bf16_kernel(const float* __restrict__ src,
                                                                 unsigned short* __restrict__ dst,
                                                                 int sstride, int dstride,
                                                                 long sBatch, long dBatch) {
  __shared__ float tile[32][33];
  long b = blockIdx.z;
  src += b * sBatch; dst += b * dBatch;
  int c0 = blockIdx.x * 32, r0 = blockIdx.y * 32;
  int tx = threadIdx.x & 31, ty = threadIdx.x >> 5;
#pragma unroll
  for (int i = 0; i < 4; ++i)
    tile[ty + i * 8][tx] = src[(size_t)(r0 + ty + i * 8) * sstride + c0 + tx];
  __syncthreads();
#pragma unroll
  for (int i = 0; i < 4; ++i)
    dst[(size_t)(c0 + ty + i * 8) * dstride + r0 + tx] = f2bf(tile[tx][ty + i * 8]);
}

// ---------------- bf16 [R][C] -> bf16 [C][R] transpose (batched) ----------------
__global__ __launch_bounds__(256) void transpose_bf16_kernel(const unsigned short* __restrict__ src,
                                                             unsigned short* __restrict__ dst,
                                                             int sstride, int dstride,
                                                             long sBatch, long dBatch) {
  __shared__ unsigned short tile[32][33];
  long b = blockIdx.z;
  src += b * sBatch; dst += b * dBatch;
  int c0 = blockIdx.x * 32, r0 = blockIdx.y * 32;
  int tx = threadIdx.x & 31, ty = threadIdx.x >> 5;
#pragma unroll
  for (int i = 0; i < 4; ++i)
    tile[ty + i * 8][tx] = src[(size_t)(r0 + ty + i * 8) * sstride + c0 + tx];
  __syncthreads();
#pragma unroll
  for (int i = 0; i < 4; ++i)
    dst[(size_t)(c0 + ty + i * 8) * dstride + r0 + tx] = tile[tx][ty + i * 8];
}

// ---------------- GEMM: C[M][N] = A[M][K] * Bt[N][K]^T (bf16 in, f32 acc) ----------------
template <int OUT_BF16>
__global__ __launch_bounds__(256) void gemm_bt_kernel(const unsigned short* __restrict__ A,
                                                      const unsigned short* __restrict__ Bt,
                                                      void* __restrict__ Cout,
                                                      int M, int N, int K) {
  __shared__ unsigned short As[128][72];   // pad 72 -> conflict-light, 16B aligned rows
  __shared__ unsigned short Bs[128][72];
  const int tid = threadIdx.x;
  const int lane = tid & 63;
  const int wave = tid >> 6;
  const int lr = lane & 15, lg = lane >> 4;
  const long brow = (long)blockIdx.y * 128, bcol = (long)blockIdx.x * 128;
  const int wr = (wave >> 1) * 64, wc = (wave & 1) * 64;
  f32x4 acc[4][4] = {};
  const int sr = tid >> 1;            // 0..127
  const int sc = (tid & 1) * 32;      // 0 / 32
  const unsigned short* pA = A + (size_t)(brow + sr) * K + sc;
  const unsigned short* pB = Bt + (size_t)(bcol + sr) * K + sc;
  for (int k0 = 0; k0 < K; k0 += 64) {
    ushort8 ra0 = *(const ushort8*)(pA + k0);
    ushort8 ra1 = *(const ushort8*)(pA + k0 + 8);
    ushort8 ra2 = *(const ushort8*)(pA + k0 + 16);
    ushort8 ra3 = *(const ushort8*)(pA + k0 + 24);
    ushort8 rb0 = *(const ushort8*)(pB + k0);
    ushort8 rb1 = *(const ushort8*)(pB + k0 + 8);
    ushort8 rb2 = *(const ushort8*)(pB + k0 + 16);
    ushort8 rb3 = *(const ushort8*)(pB + k0 + 24);
    __syncthreads();
    *(ushort8*)&As[sr][sc]      = ra0;
    *(ushort8*)&As[sr][sc + 8]  = ra1;
    *(ushort8*)&As[sr][sc + 16] = ra2;
    *(ushort8*)&As[sr][sc + 24] = ra3;
    *(ushort8*)&Bs[sr][sc]      = rb0;
    *(ushort8*)&Bs[sr][sc + 8]  = rb1;
    *(ushort8*)&Bs[sr][sc + 16] = rb2;
    *(ushort8*)&Bs[sr][sc + 24] = rb3;
    __syncthreads();
#pragma unroll
    for (int kk = 0; kk < 64; kk += 32) {
      short8 af[4], bfr[4];
#pragma unroll
      for (int m = 0; m < 4; ++m) af[m] = *(const short8*)&As[wr + m * 16 + lr][kk + lg * 8];
#pragma unroll
      for (int n = 0; n < 4; ++n) bfr[n] = *(const short8*)&Bs[wc + n * 16 + lr][kk + lg * 8];
#pragma unroll
      for (int m = 0; m < 4; ++m)
#pragma unroll
        for (int n = 0; n < 4; ++n)
          acc[m][n] = __builtin_amdgcn_mfma_f32_16x16x32_bf16(af[m], bfr[n], acc[m][n], 0, 0, 0);
    }
  }
#pragma unroll
  for (int m = 0; m < 4; ++m) {
#pragma unroll
    for (int i = 0; i < 4; ++i) {
      long row = brow + wr + m * 16 + lg * 4 + i;
#pragma unroll
      for (int n = 0; n < 4; ++n) {
        long col = bcol + wc + n * 16 + lr;
        if (OUT_BF16)
          ((unsigned short*)Cout)[row * N + col] = f2bf(acc[m][n][i]);
        else
          ((float*)Cout)[row * N + col] = acc[m][n][i];
      }
    }
  }
}

// ---------------- RoPE apply: raw qkv -> Qb [16][T][128], Kb [8][T][128] ----------------
__global__ __launch_bounds__(256) void rope_apply_kernel(const unsigned short* __restrict__ raw,
                                                         const float2* __restrict__ tab,
                                                         unsigned short* __restrict__ Qb,
                                                         unsigned short* __restrict__ Kb) {
  int gid = blockIdx.x * 256 + threadIdx.x;   // T * 24 * 8
  int j = gid & 7;
  int rem = gid >> 3;
  int hs = rem % 24;
  int t = rem / 24;
  int i0 = j * 8;
  float sv[8], cv[8];
  const float2* tp = tab + t * 64 + i0;
#pragma unroll
  for (int q = 0; q < 8; ++q) { float2 sc2 = tp[q]; sv[q] = sc2.x; cv[q] = sc2.y; }
  if (hs < 16) {
    const unsigned short* p = raw + (size_t)t * 4096 + hs * 128 + i0;
    ushort8 a = *(const ushort8*)p;
    ushort8 b = *(const ushort8*)(p + 64);
    ushort8 o1, o2;
#pragma unroll
    for (int q = 0; q < 8; ++q) {
      float fa = bf2f(a[q]), fb = bf2f(b[q]);
      o1[q] = f2bf((fa * cv[q] - fb * sv[q]) * QSCALE);
      o2[q] = f2bf((fb * cv[q] + fa * sv[q]) * QSCALE);
    }
    unsigned short* qp = Qb + ((size_t)hs * T_SEQ + t) * 128 + i0;
    *(ushort8*)qp = o1;
    *(ushort8*)(qp + 64) = o2;
  } else {
    int kn = hs - 16;
    const unsigned short* p = raw + (size_t)t * 4096 + 2048 + kn * 128 + i0;
    ushort8 a = *(const ushort8*)p;
    ushort8 b = *(const ushort8*)(p + 64);
    ushort8 o1, o2;
#pragma unroll
    for (int q = 0; q < 8; ++q) {
      float fa = bf2f(a[q]), fb = bf2f(b[q]);
      o1[q] = f2bf(fa * cv[q] - fb * sv[q]);
      o2[q] = f2bf(fb * cv[q] + fa * sv[q]);
    }
    unsigned short* kp = Kb + ((size_t)kn * T_SEQ + t) * 128 + i0;
    *(ushort8*)kp = o1;
    *(ushort8*)(kp + 64) = o2;
  }
}

// ---------------- Flash attention with sliding window + tanh soft-cap ----------------
__global__ __launch_bounds__(256) void attn_kernel(const unsigned short* __restrict__ Qb,
                                                   const unsigned short* __restrict__ Kb,
                                                   const unsigned short* __restrict__ Vt,
                                                   unsigned short* __restrict__ enc) {
  __shared__ unsigned short Ks[32][136];    // K block [32 s][128 d], padded
  __shared__ unsigned short Vts[128][40];   // V^T block [128 d][32 s], padded
  __shared__ unsigned short Ps[4][16][40];  // per-wave P round-trip
  const int h = blockIdx.y, kvh = h >> 1;
  const int qb0 = blockIdx.x * 64;
  const int tid = threadIdx.x, lane = tid & 63, wave = tid >> 6;
  const int qw = qb0 + wave * 16;
  const int lr = lane & 15, lg = lane >> 4;

  short8 aq[4];
  {
    const unsigned short* qp = Qb + ((size_t)h * T_SEQ + qw + lr) * 128 + lg * 8;
#pragma unroll
    for (int c = 0; c < 4; ++c) aq[c] = *(const short8*)(qp + c * 32);
  }
  f32x4 acc[8] = {};
  float m_run[4], l_run[4];
#pragma unroll
  for (int r = 0; r < 4; ++r) { m_run[r] = -1e30f; l_run[r] = 0.f; }

  const int s_lo = (qb0 - 1023) > 0 ? (qb0 - 1023) : 0;
  const int kb_lo = s_lo >> 5, kb_hi = (qb0 + 63) >> 5;

  const int kst = tid >> 3;           // 0..31  key row
  const int ksd = (tid & 7) * 16;     // d offset
  const int vsd = tid >> 1;           // 0..127 d row
  const int vst = (tid & 1) * 16;     // s offset
  const unsigned short* kbase = Kb + ((size_t)kvh * T_SEQ + kst) * 128 + ksd;
  const unsigned short* vbase = Vt + ((size_t)kvh * 128 + vsd) * T_SEQ + vst;

  for (int kb = kb_lo; kb <= kb_hi; ++kb) {
    const int s0g = kb * 32;
    ushort8 k0v = *(const ushort8*)(kbase + (size_t)s0g * 128);
    ushort8 k1v = *(const ushort8*)(kbase + (size_t)s0g * 128 + 8);
    ushort8 v0v = *(const ushort8*)(vbase + s0g);
    ushort8 v1v = *(const ushort8*)(vbase + s0g + 8);
    __syncthreads();
    *(ushort8*)&Ks[kst][ksd] = k0v;
    *(ushort8*)&Ks[kst][ksd + 8] = k1v;
    *(ushort8*)&Vts[vsd][vst] = v0v;
    *(ushort8*)&Vts[vsd][vst + 8] = v1v;
    __syncthreads();

    f32x4 s0 = {}, s1 = {};
#pragma unroll
    for (int c = 0; c < 4; ++c) {
      short8 b0 = *(const short8*)&Ks[lr][c * 32 + lg * 8];
      short8 b1 = *(const short8*)&Ks[16 + lr][c * 32 + lg * 8];
      s0 = __builtin_amdgcn_mfma_f32_16x16x32_bf16(aq[c], b0, s0, 0, 0, 0);
      s1 = __builtin_amdgcn_mfma_f32_16x16x32_bf16(aq[c], b1, s1, 0, 0, 0);
    }
#pragma unroll
    for (int r = 0; r < 4; ++r) {
      int qg = qw + lg * 4 + r;
      float x0 = 50.f - 100.f / (__expf(s0[r] * 0.04f) + 1.f);   // 50*tanh(x/50)
      float x1 = 50.f - 100.f / (__expf(s1[r] * 0.04f) + 1.f);
      int sg0 = s0g + lr, sg1 = s0g + 16 + lr;
      bool ok0 = (sg0 <= qg) && (sg0 >= qg - 1023);
      bool ok1 = (sg1 <= qg) && (sg1 >= qg - 1023);
      x0 = ok0 ? x0 : -3e38f;
      x1 = ok1 ? x1 : -3e38f;
      float rm = fmaxf(x0, x1);
      rm = fmaxf(rm, __shfl_xor(rm, 1));
      rm = fmaxf(rm, __shfl_xor(rm, 2));
      rm = fmaxf(rm, __shfl_xor(rm, 4));
      rm = fmaxf(rm, __shfl_xor(rm, 8));
      float mn = fmaxf(m_run[r], rm);
      float sc = __expf(m_run[r] - mn);
      float p0 = __expf(x0 - mn), p1 = __expf(x1 - mn);
      float rs = p0 + p1;
      rs += __shfl_xor(rs, 1);
      rs += __shfl_xor(rs, 2);
      rs += __shfl_xor(rs, 4);
      rs += __shfl_xor(rs, 8);
      l_run[r] = l_run[r] * sc + rs;
      m_run[r] = mn;
#pragma unroll
      for (int d = 0; d < 8; ++d) acc[d][r] *= sc;
      Ps[wave][lg * 4 + r][lr] = f2bf(p0);
      Ps[wave][lg * 4 + r][16 + lr] = f2bf(p1);
    }
    short8 pa = *(const short8*)&Ps[wave][lr][lg * 8];
#pragma unroll
    for (int d = 0; d < 8; ++d) {
      short8 bv = *(const short8*)&Vts[d * 16 + lr][lg * 8];
      acc[d] = __builtin_amdgcn_mfma_f32_16x16x32_bf16(pa, bv, acc[d], 0, 0, 0);
    }
  }
#pragma unroll
  for (int r = 0; r < 4; ++r) {
    float inv = 1.f / l_run[r];
    int row = qw + lg * 4 + r;
    unsigned short* op = enc + (size_t)row * D_MODEL + h * 128 + lr;
#pragma unroll
    for (int d = 0; d < 8; ++d) op[d * 16] = f2bf(acc[d][r] * inv);
  }
}

// ---------------- launch ----------------
extern "C" void kernel_launch(void* const* d_in, const int* in_sizes, int n_in,
                              void* d_out, int out_size, void* d_ws, size_t ws_size,
                              hipStream_t stream) {
  const float* x = (const float*)d_in[0];
  const int* segpos = (const int*)d_in[1];
  // d_in[2]: attn_mask (pure causal tril) — computed analytically, not read
  const float* q_w = (const float*)d_in[3];
  const float* kv_w = (const float*)d_in[4];
  const float* o_w = (const float*)d_in[5];
  float* out = (float*)d_out;
  char* ws = (char*)d_ws;

  const size_t OFF_XB = 0;                       // 16.8 MB  x bf16 [4096][2048]
  const size_t OFF_WT = OFF_XB + 16777216;       // 16.8 MB  Wqkv^T bf16 [4096][2048]
  const size_t OFF_RAW = OFF_WT + 16777216;      // 33.6 MB  qkv raw bf16 [4096][4096]
  const size_t OFF_KB = OFF_RAW + 33554432;      // 8.4 MB   K roped [8][4096][128]
  const size_t OFF_VT = OFF_KB + 8388608;        // 8.4 MB   V^T [8][128][4096]
  const size_t OFF_TAB = OFF_VT + 8388608;       // 2 MB     rope table
  unsigned short* xb = (unsigned short*)(ws + OFF_XB);
  unsigned short* Wt = (unsigned short*)(ws + OFF_WT);
  unsigned short* raw = (unsigned short*)(ws + OFF_RAW);
  unsigned short* Kb = (unsigned short*)(ws + OFF_KB);
  unsigned short* Vt = (unsigned short*)(ws + OFF_VT);
  float2* tab = (float2*)(ws + OFF_TAB);
  unsigned short* o_wt = xb;   // alias: built after qkv GEMM consumed xb
  unsigned short* Qb = Wt;     // alias: built after qkv GEMM consumed Wt
  unsigned short* enc = raw;   // alias: written after V transpose consumed raw

  cvt_x_kernel<<<dim3(4096), dim3(256), 0, stream>>>(x, xb);
  rope_table_kernel<<<dim3(1024), dim3(256), 0, stream>>>(segpos, tab);
  // q_w [16][2048][128] -> Wt rows 0..2047
  transpose_f32_bf16_kernel<<<dim3(4, 64, 16), dim3(256), 0, stream>>>(
      q_w, Wt, 128, 2048, (long)2048 * 128, (long)128 * 2048);
  // kv_w [2][8][2048][128] -> Wt rows 2048..4095
  transpose_f32_bf16_kernel<<<dim3(4, 64, 16), dim3(256), 0, stream>>>(
      kv_w, Wt + (size_t)2048 * 2048, 128, 2048, (long)2048 * 128, (long)128 * 2048);
  // qkv projection
  gemm_bt_kernel<1><<<dim3(32, 32), dim3(256), 0, stream>>>(xb, Wt, (void*)raw, 4096, 4096, 2048);
  // o_w [2048][2048] -> o_wt (aliases xb, now dead)
  transpose_f32_bf16_kernel<<<dim3(64, 64, 1), dim3(256), 0, stream>>>(
      o_w, o_wt, 2048, 2048, 0L, 0L);
  // rope + scale + head-major layout (Qb aliases Wt, now dead)
  rope_apply_kernel<<<dim3(3072), dim3(256), 0, stream>>>(raw, tab, Qb, Kb);
  // V -> V^T per kv head
  transpose_bf16_kernel<<<dim3(4, 128, 8), dim3(256), 0, stream>>>(
      raw + 3072, Vt, 4096, 4096, 128L, (long)128 * 4096);
  // flash attention (enc aliases raw, whose live V columns were consumed above)
  attn_kernel<<<dim3(64, 16), dim3(256), 0, stream>>>(Qb, Kb, Vt, enc);
  // output projection -> d_out (f32)
  gemm_bt_kernel<0><<<dim3(16, 32), dim3(256), 0, stream>>>(enc, o_wt, (void*)out, 4096, 2048, 2048);
}

// Round 2
// 247.784 us; speedup vs baseline: 1.3481x; 1.3481x over previous
//
#include <hip/hip_runtime.h>
#include <hip/hip_bf16.h>
#include <math.h>

typedef __attribute__((ext_vector_type(8))) short short8;
typedef __attribute__((ext_vector_type(8))) unsigned short ushort8;
typedef __attribute__((ext_vector_type(4))) float f32x4;

#define T_SEQ 4096
#define D_MODEL 2048
#define N_HEADS 16
#define N_KV 8
#define HEAD_DIM 128
#define QSCALE 0.08838834764831845f

__device__ __forceinline__ float bf2f(unsigned short u) {
  union { unsigned int i; float f; } x; x.i = ((unsigned int)u) << 16; return x.f;
}
__device__ __forceinline__ unsigned short f2bf(float f) {
  union { float f; unsigned int i; } x; x.f = f;
  unsigned int i = x.i;
  unsigned int r = i + 0x7fffu + ((i >> 16) & 1u);
  return (unsigned short)(r >> 16);
}

// ---------------- x (f32) -> bf16 ----------------
__global__ __launch_bounds__(256) void cvt_x_kernel(const float* __restrict__ x,
                                                    unsigned short* __restrict__ xb) {
  int idx = blockIdx.x * 256 + threadIdx.x;   // one thread = 8 elements
  const float4* p = reinterpret_cast<const float4*>(x) + (size_t)idx * 2;
  float4 a = p[0], b = p[1];
  ushort8 o;
  o[0] = f2bf(a.x); o[1] = f2bf(a.y); o[2] = f2bf(a.z); o[3] = f2bf(a.w);
  o[4] = f2bf(b.x); o[5] = f2bf(b.y); o[6] = f2bf(b.z); o[7] = f2bf(b.w);
  reinterpret_cast<ushort8*>(xb)[idx] = o;
}

// ---------------- RoPE sin/cos table ----------------
__global__ __launch_bounds__(256) void rope_table_kernel(const int* __restrict__ segpos,
                                                         float2* __restrict__ tab) {
  int idx = blockIdx.x * 256 + threadIdx.x;   // t*64 + i
  int t = idx >> 6, i = idx & 63;
  float pos = (float)segpos[t];
  float ts = powf(10000.f, (float)(2 * i) / 128.f);
  float ang = pos / ts;
  tab[idx] = make_float2(sinf(ang), cosf(ang));
}

// ---------------- f32 [R][C] -> bf16 [C][R] transpose (batched) ----------------
__global__ __launch_bounds__(256) void transpose_f32_bf16_kernel(const float* __restrict__ src,
                                                                 unsigned short* __restrict__ dst,
                                                                 int sstride, int dstride,
                                                                 long sBatch, long dBatch) {
  __shared__ float tile[32][33];
  long b = blockIdx.z;
  src += b * sBatch; dst += b * dBatch;
  int c0 = blockIdx.x * 32, r0 = blockIdx.y * 32;
  int tx = threadIdx.x & 31, ty = threadIdx.x >> 5;
#pragma unroll
  for (int i = 0; i < 4; ++i)
    tile[ty + i * 8][tx] = src[(size_t)(r0 + ty + i * 8) * sstride + c0 + tx];
  __syncthreads();
#pragma unroll
  for (int i = 0; i < 4; ++i)
    dst[(size_t)(c0 + ty + i * 8) * dstride + r0 + tx] = f2bf(tile[tx][ty + i * 8]);
}

// ---------------- bf16 [R][C] -> bf16 [C][R] transpose (batched) ----------------
__global__ __launch_bounds__(256) void transpose_bf16_kernel(const unsigned short* __restrict__ src,
                                                             unsigned short* __restrict__ dst,
                                                             int sstride, int dstride,
                                                             long sBatch, long dBatch) {
  __shared__ unsigned short tile[32][33];
  long b = blockIdx.z;
  src += b * sBatch; dst += b * dBatch;
  int c0 = blockIdx.x * 32, r0 = blockIdx.y * 32;
  int tx = threadIdx.x & 31, ty = threadIdx.x >> 5;
#pragma unroll
  for (int i = 0; i < 4; ++i)
    tile[ty + i * 8][tx] = src[(size_t)(r0 + ty + i * 8) * sstride + c0 + tx];
  __syncthreads();
#pragma unroll
  for (int i = 0; i < 4; ++i)
    dst[(size_t)(c0 + ty + i * 8) * dstride + r0 + tx] = tile[tx][ty + i * 8];
}

// ---------------- GEMM: C[M][N] = A[M][K] * Bt[N][K]^T (bf16 in, f32 acc) ----------------
template <int OUT_BF16>
__global__ __launch_bounds__(256) void gemm_bt_kernel(const unsigned short* __restrict__ A,
                                                      const unsigned short* __restrict__ Bt,
                                                      void* __restrict__ Cout,
                                                      int M, int N, int K) {
  __shared__ unsigned short As[128][72];   // pad 72 -> conflict-light, 16B aligned rows
  __shared__ unsigned short Bs[128][72];
  const int tid = threadIdx.x;
  const int lane = tid & 63;
  const int wave = tid >> 6;
  const int lr = lane & 15, lg = lane >> 4;
  const long brow = (long)blockIdx.y * 128, bcol = (long)blockIdx.x * 128;
  const int wr = (wave >> 1) * 64, wc = (wave & 1) * 64;
  f32x4 acc[4][4] = {};
  const int sr = tid >> 1;            // 0..127
  const int sc = (tid & 1) * 32;      // 0 / 32
  const unsigned short* pA = A + (size_t)(brow + sr) * K + sc;
  const unsigned short* pB = Bt + (size_t)(bcol + sr) * K + sc;
  for (int k0 = 0; k0 < K; k0 += 64) {
    ushort8 ra0 = *(const ushort8*)(pA + k0);
    ushort8 ra1 = *(const ushort8*)(pA + k0 + 8);
    ushort8 ra2 = *(const ushort8*)(pA + k0 + 16);
    ushort8 ra3 = *(const ushort8*)(pA + k0 + 24);
    ushort8 rb0 = *(const ushort8*)(pB + k0);
    ushort8 rb1 = *(const ushort8*)(pB + k0 + 8);
    ushort8 rb2 = *(const ushort8*)(pB + k0 + 16);
    ushort8 rb3 = *(const ushort8*)(pB + k0 + 24);
    __syncthreads();
    *(ushort8*)&As[sr][sc]      = ra0;
    *(ushort8*)&As[sr][sc + 8]  = ra1;
    *(ushort8*)&As[sr][sc + 16] = ra2;
    *(ushort8*)&As[sr][sc + 24] = ra3;
    *(ushort8*)&Bs[sr][sc]      = rb0;
    *(ushort8*)&Bs[sr][sc + 8]  = rb1;
    *(ushort8*)&Bs[sr][sc + 16] = rb2;
    *(ushort8*)&Bs[sr][sc + 24] = rb3;
    __syncthreads();
#pragma unroll
    for (int kk = 0; kk < 64; kk += 32) {
      short8 af[4], bfr[4];
#pragma unroll
      for (int m = 0; m < 4; ++m) af[m] = *(const short8*)&As[wr + m * 16 + lr][kk + lg * 8];
#pragma unroll
      for (int n = 0; n < 4; ++n) bfr[n] = *(const short8*)&Bs[wc + n * 16 + lr][kk + lg * 8];
#pragma unroll
      for (int m = 0; m < 4; ++m)
#pragma unroll
        for (int n = 0; n < 4; ++n)
          acc[m][n] = __builtin_amdgcn_mfma_f32_16x16x32_bf16(af[m], bfr[n], acc[m][n], 0, 0, 0);
    }
  }
#pragma unroll
  for (int m = 0; m < 4; ++m) {
#pragma unroll
    for (int i = 0; i < 4; ++i) {
      long row = brow + wr + m * 16 + lg * 4 + i;
#pragma unroll
      for (int n = 0; n < 4; ++n) {
        long col = bcol + wc + n * 16 + lr;
        if (OUT_BF16)
          ((unsigned short*)Cout)[row * N + col] = f2bf(acc[m][n][i]);
        else
          ((float*)Cout)[row * N + col] = acc[m][n][i];
      }
    }
  }
}

// ---------------- RoPE apply: raw qkv -> Qb [16][T][128], Kb [8][T][128] ----------------
__global__ __launch_bounds__(256) void rope_apply_kernel(const unsigned short* __restrict__ raw,
                                                         const float2* __restrict__ tab,
                                                         unsigned short* __restrict__ Qb,
                                                         unsigned short* __restrict__ Kb) {
  int gid = blockIdx.x * 256 + threadIdx.x;   // T * 24 * 8
  int j = gid & 7;
  int rem = gid >> 3;
  int hs = rem % 24;
  int t = rem / 24;
  int i0 = j * 8;
  float sv[8], cv[8];
  const float2* tp = tab + t * 64 + i0;
#pragma unroll
  for (int q = 0; q < 8; ++q) { float2 sc2 = tp[q]; sv[q] = sc2.x; cv[q] = sc2.y; }
  if (hs < 16) {
    const unsigned short* p = raw + (size_t)t * 4096 + hs * 128 + i0;
    ushort8 a = *(const ushort8*)p;
    ushort8 b = *(const ushort8*)(p + 64);
    ushort8 o1, o2;
#pragma unroll
    for (int q = 0; q < 8; ++q) {
      float fa = bf2f(a[q]), fb = bf2f(b[q]);
      o1[q] = f2bf((fa * cv[q] - fb * sv[q]) * QSCALE);
      o2[q] = f2bf((fb * cv[q] + fa * sv[q]) * QSCALE);
    }
    unsigned short* qp = Qb + ((size_t)hs * T_SEQ + t) * 128 + i0;
    *(ushort8*)qp = o1;
    *(ushort8*)(qp + 64) = o2;
  } else {
    int kn = hs - 16;
    const unsigned short* p = raw + (size_t)t * 4096 + 2048 + kn * 128 + i0;
    ushort8 a = *(const ushort8*)p;
    ushort8 b = *(const ushort8*)(p + 64);
    ushort8 o1, o2;
#pragma unroll
    for (int q = 0; q < 8; ++q) {
      float fa = bf2f(a[q]), fb = bf2f(b[q]);
      o1[q] = f2bf(fa * cv[q] - fb * sv[q]);
      o2[q] = f2bf(fb * cv[q] + fa * sv[q]);
    }
    unsigned short* kp = Kb + ((size_t)kn * T_SEQ + t) * 128 + i0;
    *(ushort8*)kp = o1;
    *(ushort8*)(kp + 64) = o2;
  }
}

// ---------------- Flash attention: sliding window + tanh soft-cap ----------------
// 8 waves x 16 q-rows = 128 q-rows/block, KVBLK=64, XOR-swizzled LDS,
// no online max (softcap bounds |logit|<=50 so exp() cannot overflow f32),
// per-lane l accumulation, one shfl-reduce at the end, reg-prefetch of next K/V.
__global__ __launch_bounds__(512) void attn_kernel(const unsigned short* __restrict__ Qb,
                                                   const unsigned short* __restrict__ Kb,
                                                   const unsigned short* __restrict__ Vt,
                                                   unsigned short* __restrict__ enc) {
  __shared__ unsigned short Ks[64][128];   // [key][d], col ^= (row&7)<<3
  __shared__ unsigned short Vs[128][64];   // [d][key], col ^= (row&7)<<3
  __shared__ unsigned short Ps[8][16][66]; // per-wave P round-trip, stride 66 -> conflict-free
  // XCD-aware swizzle: 512 blocks, contiguous chunk of 64 per XCD = 2 heads
  // sharing one KV head -> 2MB KV working set fits 4MB XCD L2.
  int lin = blockIdx.y * 32 + blockIdx.x;
  lin = (lin & 7) * 64 + (lin >> 3);       // bijective (512 % 8 == 0)
  const int h = lin >> 5;
  const int qb0 = (lin & 31) * 128;
  const int kvh = h >> 1;
  const int tid = threadIdx.x, lane = tid & 63, wave = tid >> 6;
  const int qw = qb0 + wave * 16;
  const int lr = lane & 15, lg = lane >> 4;
  const int sw = (lr & 7) << 3;

  short8 aq[4];
  {
    const unsigned short* qp = Qb + ((size_t)h * T_SEQ + qw + lr) * 128 + lg * 8;
#pragma unroll
    for (int c = 0; c < 4; ++c) aq[c] = *(const short8*)(qp + c * 32);
  }
  f32x4 acc[8] = {};
  float lsum[4] = {0.f, 0.f, 0.f, 0.f};

  const int s_lo = (qb0 - 1023) > 0 ? (qb0 - 1023) : 0;
  const int kb_lo = s_lo >> 6, kb_hi = (qb0 + 127) >> 6;

  // staging geometry: thread covers K rows {rK, rK+32}, V rows {rV, rV+64}
  const int rK = tid >> 4;
  const int cpK = (tid & 15) * 8;
  const int colK = cpK ^ ((rK & 7) << 3);
  const int rV = tid >> 3;
  const int cpV = (tid & 7) * 8;
  const int colV = cpV ^ ((rV & 7) << 3);
  const unsigned short* kgb = Kb + ((size_t)kvh * T_SEQ + rK) * 128 + colK;
  const unsigned short* vgb = Vt + ((size_t)kvh * 128 + rV) * T_SEQ + colV;

  ushort8 kr0, kr1, vr0, vr1;
  {
    const int s0g = kb_lo * 64;
    kr0 = *(const ushort8*)(kgb + (size_t)s0g * 128);
    kr1 = *(const ushort8*)(kgb + (size_t)(s0g + 32) * 128);
    vr0 = *(const ushort8*)(vgb + s0g);
    vr1 = *(const ushort8*)(vgb + (size_t)64 * T_SEQ + s0g);
  }

  for (int kb = kb_lo; kb <= kb_hi; ++kb) {
    const int s0g = kb * 64;
    __syncthreads();                        // previous tile's reads done
    *(ushort8*)&Ks[rK][cpK] = kr0;
    *(ushort8*)&Ks[rK + 32][cpK] = kr1;
    *(ushort8*)&Vs[rV][cpV] = vr0;
    *(ushort8*)&Vs[rV + 64][cpV] = vr1;
    __syncthreads();                        // tile staged
    if (kb < kb_hi) {                       // prefetch next tile (overlaps compute)
      const int sn = s0g + 64;
      kr0 = *(const ushort8*)(kgb + (size_t)sn * 128);
      kr1 = *(const ushort8*)(kgb + (size_t)(sn + 32) * 128);
      vr0 = *(const ushort8*)(vgb + sn);
      vr1 = *(const ushort8*)(vgb + (size_t)64 * T_SEQ + sn);
    }
    if (s0g > qw + 15 || s0g + 63 < qw - 1023) continue;  // fully masked for this wave

    f32x4 sv[4] = {};
#pragma unroll
    for (int st = 0; st < 4; ++st) {
      const int krow = st * 16 + lr;
#pragma unroll
      for (int c = 0; c < 4; ++c) {
        short8 b = *(const short8*)&Ks[krow][(c * 32 + lg * 8) ^ sw];
        sv[st] = __builtin_amdgcn_mfma_f32_16x16x32_bf16(aq[c], b, sv[st], 0, 0, 0);
      }
    }
#pragma unroll
    for (int st = 0; st < 4; ++st) {
#pragma unroll
      for (int r = 0; r < 4; ++r) {
        float s = sv[st][r];
        // 50*tanh(s/50) via Pade: s*(15+z2)/(15+6*z2), z2=(s/50)^2
        float z2 = s * s * 4.0e-4f;
        float capped = s * (15.f + z2) * __builtin_amdgcn_rcpf(fmaf(z2, 6.f, 15.f));
        float p = __expf(capped);
        int qg = qw + lg * 4 + r;
        int sg = s0g + st * 16 + lr;
        p = ((unsigned)(qg - sg) <= 1023u) ? p : 0.f;
        lsum[r] += p;
        Ps[wave][lg * 4 + r][st * 16 + lr] = f2bf(p);
      }
    }
    short8 pa0 = *(const short8*)&Ps[wave][lr][lg * 8];
    short8 pa1 = *(const short8*)&Ps[wave][lr][32 + lg * 8];
#pragma unroll
    for (int d0 = 0; d0 < 8; ++d0) {
      const int vrow = d0 * 16 + lr;
      short8 bv0 = *(const short8*)&Vs[vrow][(lg * 8) ^ sw];
      short8 bv1 = *(const short8*)&Vs[vrow][(32 + lg * 8) ^ sw];
      acc[d0] = __builtin_amdgcn_mfma_f32_16x16x32_bf16(pa0, bv0, acc[d0], 0, 0, 0);
      acc[d0] = __builtin_amdgcn_mfma_f32_16x16x32_bf16(pa1, bv1, acc[d0], 0, 0, 0);
    }
  }

#pragma unroll
  for (int r = 0; r < 4; ++r) {
    float l = lsum[r];
    l += __shfl_xor(l, 1);
    l += __shfl_xor(l, 2);
    l += __shfl_xor(l, 4);
    l += __shfl_xor(l, 8);
    float inv = __builtin_amdgcn_rcpf(l);
    int row = qw + lg * 4 + r;
    unsigned short* op = enc + (size_t)row * D_MODEL + h * 128 + lr;
#pragma unroll
    for (int d0 = 0; d0 < 8; ++d0) op[d0 * 16] = f2bf(acc[d0][r] * inv);
  }
}

// ---------------- launch ----------------
extern "C" void kernel_launch(void* const* d_in, const int* in_sizes, int n_in,
                              void* d_out, int out_size, void* d_ws, size_t ws_size,
                              hipStream_t stream) {
  const float* x = (const float*)d_in[0];
  const int* segpos = (const int*)d_in[1];
  // d_in[2]: attn_mask (pure causal tril) — computed analytically, not read
  const float* q_w = (const float*)d_in[3];
  const float* kv_w = (const float*)d_in[4];
  const float* o_w = (const float*)d_in[5];
  float* out = (float*)d_out;
  char* ws = (char*)d_ws;

  const size_t OFF_XB = 0;                       // 16.8 MB  x bf16 [4096][2048]
  const size_t OFF_WT = OFF_XB + 16777216;       // 16.8 MB  Wqkv^T bf16 [4096][2048]
  const size_t OFF_RAW = OFF_WT + 16777216;      // 33.6 MB  qkv raw bf16 [4096][4096]
  const size_t OFF_KB = OFF_RAW + 33554432;      // 8.4 MB   K roped [8][4096][128]
  const size_t OFF_VT = OFF_KB + 8388608;        // 8.4 MB   V^T [8][128][4096]
  const size_t OFF_TAB = OFF_VT + 8388608;       // 2 MB     rope table
  unsigned short* xb = (unsigned short*)(ws + OFF_XB);
  unsigned short* Wt = (unsigned short*)(ws + OFF_WT);
  unsigned short* raw = (unsigned short*)(ws + OFF_RAW);
  unsigned short* Kb = (unsigned short*)(ws + OFF_KB);
  unsigned short* Vt = (unsigned short*)(ws + OFF_VT);
  float2* tab = (float2*)(ws + OFF_TAB);
  unsigned short* o_wt = xb;   // alias: built after qkv GEMM consumed xb
  unsigned short* Qb = Wt;     // alias: built after qkv GEMM consumed Wt
  unsigned short* enc = raw;   // alias: written after V transpose consumed raw

  cvt_x_kernel<<<dim3(4096), dim3(256), 0, stream>>>(x, xb);
  rope_table_kernel<<<dim3(1024), dim3(256), 0, stream>>>(segpos, tab);
  // q_w [16][2048][128] -> Wt rows 0..2047
  transpose_f32_bf16_kernel<<<dim3(4, 64, 16), dim3(256), 0, stream>>>(
      q_w, Wt, 128, 2048, (long)2048 * 128, (long)128 * 2048);
  // kv_w [2][8][2048][128] -> Wt rows 2048..4095
  transpose_f32_bf16_kernel<<<dim3(4, 64, 16), dim3(256), 0, stream>>>(
      kv_w, Wt + (size_t)2048 * 2048, 128, 2048, (long)2048 * 128, (long)128 * 2048);
  // qkv projection
  gemm_bt_kernel<1><<<dim3(32, 32), dim3(256), 0, stream>>>(xb, Wt, (void*)raw, 4096, 4096, 2048);
  // o_w [2048][2048] -> o_wt (aliases xb, now dead)
  transpose_f32_bf16_kernel<<<dim3(64, 64, 1), dim3(256), 0, stream>>>(
      o_w, o_wt, 2048, 2048, 0L, 0L);
  // rope + scale + head-major layout (Qb aliases Wt, now dead)
  rope_apply_kernel<<<dim3(3072), dim3(256), 0, stream>>>(raw, tab, Qb, Kb);
  // V -> V^T per kv head
  transpose_bf16_kernel<<<dim3(4, 128, 8), dim3(256), 0, stream>>>(
      raw + 3072, Vt, 4096, 4096, 128L, (long)128 * 4096);
  // flash attention (enc aliases raw, whose live V columns were consumed above)
  attn_kernel<<<dim3(32, 16), dim3(512), 0, stream>>>(Qb, Kb, Vt, enc);
  // output projection -> d_out (f32)
  gemm_bt_kernel<0><<<dim3(16, 32), dim3(256), 0, stream>>>(enc, o_wt, (void*)out, 4096, 2048, 2048);
}

// Round 3
// 224.542 us; speedup vs baseline: 1.4876x; 1.1035x over previous
//
#include <hip/hip_runtime.h>
#include <hip/hip_bf16.h>
#include <math.h>

typedef __attribute__((ext_vector_type(8))) short short8;
typedef __attribute__((ext_vector_type(8))) unsigned short ushort8;
typedef __attribute__((ext_vector_type(4))) float f32x4;

#define T_SEQ 4096
#define D_MODEL 2048
#define N_HEADS 16
#define N_KV 8
#define HEAD_DIM 128
#define QSCALE 0.08838834764831845f

__device__ __forceinline__ float bf2f(unsigned short u) {
  union { unsigned int i; float f; } x; x.i = ((unsigned int)u) << 16; return x.f;
}
__device__ __forceinline__ unsigned short f2bf(float f) {
  union { float f; unsigned int i; } x; x.f = f;
  unsigned int i = x.i;
  unsigned int r = i + 0x7fffu + ((i >> 16) & 1u);
  return (unsigned short)(r >> 16);
}

// ---------------- x (f32) -> bf16 ----------------
__global__ __launch_bounds__(256) void cvt_x_kernel(const float* __restrict__ x,
                                                    unsigned short* __restrict__ xb) {
  int idx = blockIdx.x * 256 + threadIdx.x;   // one thread = 8 elements
  const float4* p = reinterpret_cast<const float4*>(x) + (size_t)idx * 2;
  float4 a = p[0], b = p[1];
  ushort8 o;
  o[0] = f2bf(a.x); o[1] = f2bf(a.y); o[2] = f2bf(a.z); o[3] = f2bf(a.w);
  o[4] = f2bf(b.x); o[5] = f2bf(b.y); o[6] = f2bf(b.z); o[7] = f2bf(b.w);
  reinterpret_cast<ushort8*>(xb)[idx] = o;
}

// ---------------- RoPE sin/cos table ----------------
__global__ __launch_bounds__(256) void rope_table_kernel(const int* __restrict__ segpos,
                                                         float2* __restrict__ tab) {
  int idx = blockIdx.x * 256 + threadIdx.x;   // t*64 + i
  int t = idx >> 6, i = idx & 63;
  float pos = (float)segpos[t];
  float ts = powf(10000.f, (float)(2 * i) / 128.f);
  float ang = pos / ts;
  tab[idx] = make_float2(sinf(ang), cosf(ang));
}

// ---------------- f32 [R][C] -> bf16 [C][R] transpose (batched) ----------------
__global__ __launch_bounds__(256) void transpose_f32_bf16_kernel(const float* __restrict__ src,
                                                                 unsigned short* __restrict__ dst,
                                                                 int sstride, int dstride,
                                                                 long sBatch, long dBatch) {
  __shared__ float tile[32][33];
  long b = blockIdx.z;
  src += b * sBatch; dst += b * dBatch;
  int c0 = blockIdx.x * 32, r0 = blockIdx.y * 32;
  int tx = threadIdx.x & 31, ty = threadIdx.x >> 5;
#pragma unroll
  for (int i = 0; i < 4; ++i)
    tile[ty + i * 8][tx] = src[(size_t)(r0 + ty + i * 8) * sstride + c0 + tx];
  __syncthreads();
#pragma unroll
  for (int i = 0; i < 4; ++i)
    dst[(size_t)(c0 + ty + i * 8) * dstride + r0 + tx] = f2bf(tile[tx][ty + i * 8]);
}

// ---------------- bf16 [R][C] -> bf16 [C][R] transpose (batched) ----------------
__global__ __launch_bounds__(256) void transpose_bf16_kernel(const unsigned short* __restrict__ src,
                                                             unsigned short* __restrict__ dst,
                                                             int sstride, int dstride,
                                                             long sBatch, long dBatch) {
  __shared__ unsigned short tile[32][33];
  long b = blockIdx.z;
  src += b * sBatch; dst += b * dBatch;
  int c0 = blockIdx.x * 32, r0 = blockIdx.y * 32;
  int tx = threadIdx.x & 31, ty = threadIdx.x >> 5;
#pragma unroll
  for (int i = 0; i < 4; ++i)
    tile[ty + i * 8][tx] = src[(size_t)(r0 + ty + i * 8) * sstride + c0 + tx];
  __syncthreads();
#pragma unroll
  for (int i = 0; i < 4; ++i)
    dst[(size_t)(c0 + ty + i * 8) * dstride + r0 + tx] = tile[tx][ty + i * 8];
}

// ---------------- GEMM: C[M][N] = A[M][K] * Bt[N][K]^T (bf16 in, f32 acc) ----------------
// global_load_lds direct staging (linear LDS dest), double-buffered, 2-phase:
// issue next tile's loads, compute current, one vmcnt(0)+barrier per K-step.
// LDS read conflict fix per rule #21: inverse-swizzled GLOBAL source + swizzled ds_read.
#define G2L(gp, lp)                                                           \
  __builtin_amdgcn_global_load_lds(                                           \
      (const __attribute__((address_space(1))) void*)(gp),                    \
      (__attribute__((address_space(3))) void*)(lp), 16, 0, 0)

template <int OUT_BF16>
__global__ __launch_bounds__(256) void gemm_bt_kernel(const unsigned short* __restrict__ A,
                                                      const unsigned short* __restrict__ Bt,
                                                      void* __restrict__ Cout,
                                                      int M, int N, int K) {
  __shared__ unsigned short As[2][128 * 64];   // linear [row][64], 16 KB each
  __shared__ unsigned short Bs[2][128 * 64];
  const int tid = threadIdx.x;
  const int lane = tid & 63;
  const int wave = tid >> 6;
  const int lr = lane & 15, lg = lane >> 4;
  const long brow = (long)blockIdx.y * 128, bcol = (long)blockIdx.x * 128;
  const int wr = (wave >> 1) * 64, wc = (wave & 1) * 64;
  f32x4 acc[4][4] = {};

  // staging geometry: element e = i*256 + tid covers LDS shorts [e*8, e*8+8)
  // = row (i*32 + tid>>3), cols [(tid&7)*8, +8). Global source column is
  // pre-XOR-swizzled so a swizzled ds_read recovers linear data (rule #21).
  const int er = tid >> 3;                       // 0..31, +i*32 per chunk
  const int ecs = ((tid & 7) * 8) ^ ((er & 7) << 3);
  const unsigned short* gA = A + (size_t)(brow + er) * K + ecs;
  const unsigned short* gB = Bt + (size_t)(bcol + er) * K + ecs;
  const int ldst = wave * 512;                   // wave-uniform LDS offset (shorts), +i*2048

#define STAGE(buf, k0)                                                        \
  {                                                                           \
    _Pragma("unroll")                                                         \
    for (int i = 0; i < 4; ++i) {                                             \
      G2L(gA + (size_t)i * 32 * K + (k0), &As[buf][i * 2048 + ldst]);         \
      G2L(gB + (size_t)i * 32 * K + (k0), &Bs[buf][i * 2048 + ldst]);         \
    }                                                                         \
  }

  const int nk = K >> 6;
  STAGE(0, 0);
  asm volatile("s_waitcnt vmcnt(0)" ::: "memory");
  __syncthreads();
  int cur = 0;
  const int swr = (lr & 7) << 3;
  for (int t = 0; t < nk; ++t) {
    if (t + 1 < nk) STAGE(cur ^ 1, (t + 1) << 6);
#pragma unroll
    for (int kk = 0; kk < 64; kk += 32) {
      short8 af[4], bfr[4];
#pragma unroll
      for (int m = 0; m < 4; ++m)
        af[m] = *(const short8*)&As[cur][(wr + m * 16 + lr) * 64 + ((kk + lg * 8) ^ swr)];
#pragma unroll
      for (int n = 0; n < 4; ++n)
        bfr[n] = *(const short8*)&Bs[cur][(wc + n * 16 + lr) * 64 + ((kk + lg * 8) ^ swr)];
#pragma unroll
      for (int m = 0; m < 4; ++m)
#pragma unroll
        for (int n = 0; n < 4; ++n)
          acc[m][n] = __builtin_amdgcn_mfma_f32_16x16x32_bf16(af[m], bfr[n], acc[m][n], 0, 0, 0);
    }
    asm volatile("s_waitcnt vmcnt(0)" ::: "memory");
    __syncthreads();
    cur ^= 1;
  }
#undef STAGE

#pragma unroll
  for (int m = 0; m < 4; ++m) {
#pragma unroll
    for (int i = 0; i < 4; ++i) {
      long row = brow + wr + m * 16 + lg * 4 + i;
#pragma unroll
      for (int n = 0; n < 4; ++n) {
        long col = bcol + wc + n * 16 + lr;
        if (OUT_BF16)
          ((unsigned short*)Cout)[row * N + col] = f2bf(acc[m][n][i]);
        else
          ((float*)Cout)[row * N + col] = acc[m][n][i];
      }
    }
  }
}

// ---------------- RoPE apply: raw qkv -> Qb [16][T][128], Kb [8][T][128] ----------------
__global__ __launch_bounds__(256) void rope_apply_kernel(const unsigned short* __restrict__ raw,
                                                         const float2* __restrict__ tab,
                                                         unsigned short* __restrict__ Qb,
                                                         unsigned short* __restrict__ Kb) {
  int gid = blockIdx.x * 256 + threadIdx.x;   // T * 24 * 8
  int j = gid & 7;
  int rem = gid >> 3;
  int hs = rem % 24;
  int t = rem / 24;
  int i0 = j * 8;
  float sv[8], cv[8];
  const float2* tp = tab + t * 64 + i0;
#pragma unroll
  for (int q = 0; q < 8; ++q) { float2 sc2 = tp[q]; sv[q] = sc2.x; cv[q] = sc2.y; }
  if (hs < 16) {
    const unsigned short* p = raw + (size_t)t * 4096 + hs * 128 + i0;
    ushort8 a = *(const ushort8*)p;
    ushort8 b = *(const ushort8*)(p + 64);
    ushort8 o1, o2;
#pragma unroll
    for (int q = 0; q < 8; ++q) {
      float fa = bf2f(a[q]), fb = bf2f(b[q]);
      o1[q] = f2bf((fa * cv[q] - fb * sv[q]) * QSCALE);
      o2[q] = f2bf((fb * cv[q] + fa * sv[q]) * QSCALE);
    }
    unsigned short* qp = Qb + ((size_t)hs * T_SEQ + t) * 128 + i0;
    *(ushort8*)qp = o1;
    *(ushort8*)(qp + 64) = o2;
  } else {
    int kn = hs - 16;
    const unsigned short* p = raw + (size_t)t * 4096 + 2048 + kn * 128 + i0;
    ushort8 a = *(const ushort8*)p;
    ushort8 b = *(const ushort8*)(p + 64);
    ushort8 o1, o2;
#pragma unroll
    for (int q = 0; q < 8; ++q) {
      float fa = bf2f(a[q]), fb = bf2f(b[q]);
      o1[q] = f2bf(fa * cv[q] - fb * sv[q]);
      o2[q] = f2bf(fb * cv[q] + fa * sv[q]);
    }
    unsigned short* kp = Kb + ((size_t)kn * T_SEQ + t) * 128 + i0;
    *(ushort8*)kp = o1;
    *(ushort8*)(kp + 64) = o2;
  }
}

// ---------------- Flash attention: sliding window + tanh soft-cap ----------------
__global__ __launch_bounds__(512) void attn_kernel(const unsigned short* __restrict__ Qb,
                                                   const unsigned short* __restrict__ Kb,
                                                   const unsigned short* __restrict__ Vt,
                                                   unsigned short* __restrict__ enc) {
  __shared__ unsigned short Ks[64][128];   // [key][d], col ^= (row&7)<<3
  __shared__ unsigned short Vs[128][64];   // [d][key], col ^= (row&7)<<3
  __shared__ unsigned short Ps[8][16][66]; // per-wave P round-trip, stride 66 -> conflict-free
  int lin = blockIdx.y * 32 + blockIdx.x;
  lin = (lin & 7) * 64 + (lin >> 3);       // bijective (512 % 8 == 0)
  const int h = lin >> 5;
  const int qb0 = (lin & 31) * 128;
  const int kvh = h >> 1;
  const int tid = threadIdx.x, lane = tid & 63, wave = tid >> 6;
  const int qw = qb0 + wave * 16;
  const int lr = lane & 15, lg = lane >> 4;
  const int sw = (lr & 7) << 3;

  short8 aq[4];
  {
    const unsigned short* qp = Qb + ((size_t)h * T_SEQ + qw + lr) * 128 + lg * 8;
#pragma unroll
    for (int c = 0; c < 4; ++c) aq[c] = *(const short8*)(qp + c * 32);
  }
  f32x4 acc[8] = {};
  float lsum[4] = {0.f, 0.f, 0.f, 0.f};

  const int s_lo = (qb0 - 1023) > 0 ? (qb0 - 1023) : 0;
  const int kb_lo = s_lo >> 6, kb_hi = (qb0 + 127) >> 6;

  const int rK = tid >> 4;
  const int cpK = (tid & 15) * 8;
  const int colK = cpK ^ ((rK & 7) << 3);
  const int rV = tid >> 3;
  const int cpV = (tid & 7) * 8;
  const int colV = cpV ^ ((rV & 7) << 3);
  const unsigned short* kgb = Kb + ((size_t)kvh * T_SEQ + rK) * 128 + colK;
  const unsigned short* vgb = Vt + ((size_t)kvh * 128 + rV) * T_SEQ + colV;

  ushort8 kr0, kr1, vr0, vr1;
  {
    const int s0g = kb_lo * 64;
    kr0 = *(const ushort8*)(kgb + (size_t)s0g * 128);
    kr1 = *(const ushort8*)(kgb + (size_t)(s0g + 32) * 128);
    vr0 = *(const ushort8*)(vgb + s0g);
    vr1 = *(const ushort8*)(vgb + (size_t)64 * T_SEQ + s0g);
  }

  for (int kb = kb_lo; kb <= kb_hi; ++kb) {
    const int s0g = kb * 64;
    __syncthreads();
    *(ushort8*)&Ks[rK][cpK] = kr0;
    *(ushort8*)&Ks[rK + 32][cpK] = kr1;
    *(ushort8*)&Vs[rV][cpV] = vr0;
    *(ushort8*)&Vs[rV + 64][cpV] = vr1;
    __syncthreads();
    if (kb < kb_hi) {
      const int sn = s0g + 64;
      kr0 = *(const ushort8*)(kgb + (size_t)sn * 128);
      kr1 = *(const ushort8*)(kgb + (size_t)(sn + 32) * 128);
      vr0 = *(const ushort8*)(vgb + sn);
      vr1 = *(const ushort8*)(vgb + (size_t)64 * T_SEQ + sn);
    }
    if (s0g > qw + 15 || s0g + 63 < qw - 1023) continue;

    f32x4 sv[4] = {};
#pragma unroll
    for (int st = 0; st < 4; ++st) {
      const int krow = st * 16 + lr;
#pragma unroll
      for (int c = 0; c < 4; ++c) {
        short8 b = *(const short8*)&Ks[krow][(c * 32 + lg * 8) ^ sw];
        sv[st] = __builtin_amdgcn_mfma_f32_16x16x32_bf16(aq[c], b, sv[st], 0, 0, 0);
      }
    }
#pragma unroll
    for (int st = 0; st < 4; ++st) {
#pragma unroll
      for (int r = 0; r < 4; ++r) {
        float s = sv[st][r];
        float z2 = s * s * 4.0e-4f;
        float capped = s * (15.f + z2) * __builtin_amdgcn_rcpf(fmaf(z2, 6.f, 15.f));
        float p = __expf(capped);
        int qg = qw + lg * 4 + r;
        int sg = s0g + st * 16 + lr;
        p = ((unsigned)(qg - sg) <= 1023u) ? p : 0.f;
        lsum[r] += p;
        Ps[wave][lg * 4 + r][st * 16 + lr] = f2bf(p);
      }
    }
    short8 pa0 = *(const short8*)&Ps[wave][lr][lg * 8];
    short8 pa1 = *(const short8*)&Ps[wave][lr][32 + lg * 8];
#pragma unroll
    for (int d0 = 0; d0 < 8; ++d0) {
      const int vrow = d0 * 16 + lr;
      short8 bv0 = *(const short8*)&Vs[vrow][(lg * 8) ^ sw];
      short8 bv1 = *(const short8*)&Vs[vrow][(32 + lg * 8) ^ sw];
      acc[d0] = __builtin_amdgcn_mfma_f32_16x16x32_bf16(pa0, bv0, acc[d0], 0, 0, 0);
      acc[d0] = __builtin_amdgcn_mfma_f32_16x16x32_bf16(pa1, bv1, acc[d0], 0, 0, 0);
    }
  }

#pragma unroll
  for (int r = 0; r < 4; ++r) {
    float l = lsum[r];
    l += __shfl_xor(l, 1);
    l += __shfl_xor(l, 2);
    l += __shfl_xor(l, 4);
    l += __shfl_xor(l, 8);
    float inv = __builtin_amdgcn_rcpf(l);
    int row = qw + lg * 4 + r;
    unsigned short* op = enc + (size_t)row * D_MODEL + h * 128 + lr;
#pragma unroll
    for (int d0 = 0; d0 < 8; ++d0) op[d0 * 16] = f2bf(acc[d0][r] * inv);
  }
}

// ---------------- launch ----------------
extern "C" void kernel_launch(void* const* d_in, const int* in_sizes, int n_in,
                              void* d_out, int out_size, void* d_ws, size_t ws_size,
                              hipStream_t stream) {
  const float* x = (const float*)d_in[0];
  const int* segpos = (const int*)d_in[1];
  // d_in[2]: attn_mask (pure causal tril) — computed analytically, not read
  const float* q_w = (const float*)d_in[3];
  const float* kv_w = (const float*)d_in[4];
  const float* o_w = (const float*)d_in[5];
  float* out = (float*)d_out;
  char* ws = (char*)d_ws;

  const size_t OFF_XB = 0;                       // 16.8 MB  x bf16 [4096][2048]
  const size_t OFF_WT = OFF_XB + 16777216;       // 16.8 MB  Wqkv^T bf16 [4096][2048]
  const size_t OFF_RAW = OFF_WT + 16777216;      // 33.6 MB  qkv raw bf16 [4096][4096]
  const size_t OFF_KB = OFF_RAW + 33554432;      // 8.4 MB   K roped [8][4096][128]
  const size_t OFF_VT = OFF_KB + 8388608;        // 8.4 MB   V^T [8][128][4096]
  const size_t OFF_TAB = OFF_VT + 8388608;       // 2 MB     rope table
  unsigned short* xb = (unsigned short*)(ws + OFF_XB);
  unsigned short* Wt = (unsigned short*)(ws + OFF_WT);
  unsigned short* raw = (unsigned short*)(ws + OFF_RAW);
  unsigned short* Kb = (unsigned short*)(ws + OFF_KB);
  unsigned short* Vt = (unsigned short*)(ws + OFF_VT);
  float2* tab = (float2*)(ws + OFF_TAB);
  unsigned short* o_wt = xb;   // alias: built after qkv GEMM consumed xb
  unsigned short* Qb = Wt;     // alias: built after qkv GEMM consumed Wt
  unsigned short* enc = raw;   // alias: written after V transpose consumed raw

  cvt_x_kernel<<<dim3(4096), dim3(256), 0, stream>>>(x, xb);
  rope_table_kernel<<<dim3(1024), dim3(256), 0, stream>>>(segpos, tab);
  transpose_f32_bf16_kernel<<<dim3(4, 64, 16), dim3(256), 0, stream>>>(
      q_w, Wt, 128, 2048, (long)2048 * 128, (long)128 * 2048);
  transpose_f32_bf16_kernel<<<dim3(4, 64, 16), dim3(256), 0, stream>>>(
      kv_w, Wt + (size_t)2048 * 2048, 128, 2048, (long)2048 * 128, (long)128 * 2048);
  gemm_bt_kernel<1><<<dim3(32, 32), dim3(256), 0, stream>>>(xb, Wt, (void*)raw, 4096, 4096, 2048);
  transpose_f32_bf16_kernel<<<dim3(64, 64, 1), dim3(256), 0, stream>>>(
      o_w, o_wt, 2048, 2048, 0L, 0L);
  rope_apply_kernel<<<dim3(3072), dim3(256), 0, stream>>>(raw, tab, Qb, Kb);
  transpose_bf16_kernel<<<dim3(4, 128, 8), dim3(256), 0, stream>>>(
      raw + 3072, Vt, 4096, 4096, 128L, (long)128 * 4096);
  attn_kernel<<<dim3(32, 16), dim3(512), 0, stream>>>(Qb, Kb, Vt, enc);
  gemm_bt_kernel<0><<<dim3(16, 32), dim3(256), 0, stream>>>(enc, o_wt, (void*)out, 4096, 2048, 2048);
}